// Round 11
// baseline (180.416 us; speedup 1.0000x reference)
//
#include <hip/hip_runtime.h>
#include <hip/hip_bf16.h>
#include <math.h>

namespace {

constexpr int T  = 2048;
constexpr int HD = 64;
constexpr float EPS = 1.1920929e-07f;
// SCALE * log2(e), folded into q at proj_q write time -> attn softmax runs in exp2 domain
constexpr float PS = 0.125f * 1.44269504f;

// bf16 weight pool offsets (in elements)
constexpr int OFF_DQ  = 0;       // 512*64
constexpr int OFF_UQ  = 32768;   // 64*512
constexpr int OFF_DKV = 65536;   // 1024*64
constexpr int OFF_UKV = 131072;  // 128*1024
constexpr int OFF_QR  = 262144;  // 64*64
constexpr int OFF_KR  = 266240;  // 64*64
constexpr int OFF_O   = 270336;  // 64*64
constexpr int W_TOTAL = 274432;

typedef __attribute__((ext_vector_type(8))) short bf8v;  // 8 bf16 (4 VGPR)
typedef __attribute__((ext_vector_type(4))) float f4v;   // MFMA C/D

#define MFMA16(a, b, c) __builtin_amdgcn_mfma_f32_16x16x32_bf16((a), (b), (c), 0, 0, 0)

// full-strength barrier for raw s_barrier use (rule #18 class): compiler
// memory fences both sides so gload_lds issues can't be hoisted across.
#define HARD_BARRIER()                                   \
  do {                                                   \
    asm volatile("" ::: "memory");                       \
    __builtin_amdgcn_s_barrier();                        \
    asm volatile("" ::: "memory");                       \
    __builtin_amdgcn_sched_barrier(0);                   \
  } while (0)

__device__ __forceinline__ short f2bf(float f) {
  union { float f; unsigned u; } v; v.f = f;
  unsigned r = v.u + 0x7FFFu + ((v.u >> 16) & 1u); // RNE
  return (short)(r >> 16);
}

__device__ __forceinline__ f4v z4() { f4v z = {0.f, 0.f, 0.f, 0.f}; return z; }

// XOR swizzles: spread row-strided b128 accesses across banks (m214 pattern)
__device__ __forceinline__ int swz128(int b) { return b ^ (((b >> 7) & 7) << 4); }
__device__ __forceinline__ int swz256(int b) { return b ^ (((b >> 8) & 7) << 4); }

__device__ __forceinline__ bf8v ldA128(const short* lds, int row, int k) {
  return *(const bf8v*)((const char*)lds + swz128(row * 128 + k * 2));
}
__device__ __forceinline__ bf8v ldA256(const short* lds, int row, int k) {
  return *(const bf8v*)((const char*)lds + swz256(row * 256 + k * 2));
}

// scatter a 16x16 D-fragment (col=lane&15, row=(lane>>4)*4+r) as bf16 into LDS
__device__ __forceinline__ void scat128(short* lds, int row0, int lane, int nt, f4v v) {
  int col = nt * 16 + (lane & 15);
  int r0 = row0 + ((lane >> 4) << 2);
#pragma unroll
  for (int r = 0; r < 4; ++r)
    *(short*)((char*)lds + swz128((r0 + r) * 128 + col * 2)) = f2bf(v[r]);
}
__device__ __forceinline__ void scat256(short* lds, int row0, int lane, int col, f4v v) {
  int r0 = row0 + ((lane >> 4) << 2);
#pragma unroll
  for (int r = 0; r < 4; ++r)
    *(short*)((char*)lds + swz256((r0 + r) * 256 + col * 2)) = f2bf(v[r]);
}

// async global->LDS, 16B per lane; LDS dest wave-uniform base + lane*16
__device__ __forceinline__ void gload_lds16(const void* g, void* l) {
  __builtin_amdgcn_global_load_lds(
      (const __attribute__((address_space(1))) void*)g,
      (__attribute__((address_space(3))) void*)l, 16, 0, 0);
}

// ---------------------------------------------------------------------------
// conversions
// ---------------------------------------------------------------------------
__global__ __launch_bounds__(256) void cvt_x_kernel(const float* __restrict__ x,
                                                    short* __restrict__ xb) {
  int i = (blockIdx.x * 256 + threadIdx.x) * 4; // over x linear (B,T,D)
  float4 v = *(const float4*)(x + i);
  int d = i & 1023, t = (i >> 10) & 2047, b = i >> 21;
  int h = d >> 6, dd = d & 63;
  short4 o;
  o.x = f2bf(v.x); o.y = f2bf(v.y); o.z = f2bf(v.z); o.w = f2bf(v.w);
  *(short4*)(xb + ((((size_t)b * 16 + h) * T + t) * 64 + dd)) = o;
}

__global__ __launch_bounds__(256) void cvt_w_kernel(
    const float* __restrict__ W_DQ, const float* __restrict__ W_UQ,
    const float* __restrict__ W_DKV, const float* __restrict__ W_UKV,
    const float* __restrict__ W_QR, const float* __restrict__ W_KR,
    const float* __restrict__ W_O, short* __restrict__ wb) {
  int i = blockIdx.x * 256 + threadIdx.x;
  const float* src; int off;
  if      (i < 32768)  { src = W_DQ;  off = 0; }
  else if (i < 65536)  { src = W_UQ;  off = 32768; }
  else if (i < 131072) { src = W_DKV; off = 65536; }
  else if (i < 262144) { src = W_UKV; off = 131072; }
  else if (i < 266240) { src = W_QR;  off = 262144; }
  else if (i < 270336) { src = W_KR;  off = 266240; }
  else                 { src = W_O;   off = 270336; }
  wb[i] = f2bf(src[i - off]);
}

// ---------------------------------------------------------------------------
// proj_q v2 (unchanged from round 10; __syncthreads-based, airtight)
// ---------------------------------------------------------------------------
__global__ __launch_bounds__(256) void proj_q_mfma(
    const short* __restrict__ xb, const short* __restrict__ wb,
    const float* __restrict__ qnw, short* __restrict__ qb) {
  __shared__ __attribute__((aligned(16))) short Xs[128 * 64];   // 16KB
  __shared__ __attribute__((aligned(16))) short Wd[2][64 * 64]; // 2x8KB
  __shared__ __attribute__((aligned(16))) short Wu[2][64 * 64]; // 2x8KB
  __shared__ __attribute__((aligned(16))) short Cs[128 * 64];   // 16KB

  const int tid = threadIdx.x, lane = tid & 63, w = tid >> 6;
  const int bh = blockIdx.y, t0 = blockIdx.x * 128;
  const int c16 = lane & 15;
  const int koff = (lane >> 4) << 3;

  auto stageWd = [&](int lc) {
    const char* src = (const char*)(wb + OFF_DQ + lc * 64 * 64);
    char* dst = (char*)&Wd[lc & 1][0];
#pragma unroll
    for (int p = 0; p < 2; ++p) {
      const int base = p * 256 + w * 64;
      gload_lds16(src + swz128((base + lane) * 16), dst + base * 16);
    }
  };
  auto stageWu = [&](int lc) {
    const char* src = (const char*)(wb + OFF_UQ + lc * 64);
    char* dst = (char*)&Wu[lc & 1][0];
#pragma unroll
    for (int p = 0; p < 2; ++p) {
      const int base = p * 256 + w * 64;
      const int lb = swz128((base + lane) * 16);
      gload_lds16(src + (size_t)(lb >> 7) * 1024 + (lb & 127), dst + base * 16);
    }
  };

  {
    const char* src = (const char*)(xb + ((size_t)bh * T + t0) * 64);
#pragma unroll
    for (int p = 0; p < 4; ++p) {
      const int base = p * 256 + w * 64;
      gload_lds16(src + swz128((base + lane) * 16), (char*)Xs + base * 16);
    }
  }
  stageWd(0);
  stageWu(0);
  __syncthreads();

  f4v acc[2][4];
#pragma unroll
  for (int rg = 0; rg < 2; ++rg)
#pragma unroll
    for (int nt = 0; nt < 4; ++nt) acc[rg][nt] = z4();

  for (int lc = 0; lc < 8; ++lc) {
    if (lc < 7) { stageWd(lc + 1); stageWu(lc + 1); }
    else {
      const char* src = (const char*)(wb + OFF_QR);
      char* dst = (char*)&Wd[0][0];
#pragma unroll
      for (int p = 0; p < 2; ++p) {
        const int base = p * 256 + w * 64;
        gload_lds16(src + swz128((base + lane) * 16), dst + base * 16);
      }
    }
    const short* Wdc = &Wd[lc & 1][0];
    const short* Wuc = &Wu[lc & 1][0];

    f4v cc[2][4];
#pragma unroll
    for (int rg = 0; rg < 2; ++rg)
#pragma unroll
      for (int nt = 0; nt < 4; ++nt) cc[rg][nt] = z4();
#pragma unroll
    for (int rg = 0; rg < 2; ++rg)
#pragma unroll
      for (int ks = 0; ks < 2; ++ks) {
        bf8v a = ldA128(Xs, w * 32 + rg * 16 + c16, ks * 32 + koff);
#pragma unroll
        for (int nt = 0; nt < 4; ++nt) {
          bf8v b = ldA128(Wdc, nt * 16 + c16, ks * 32 + koff);
          cc[rg][nt] = MFMA16(a, b, cc[rg][nt]);
        }
      }
#pragma unroll
    for (int rg = 0; rg < 2; ++rg)
#pragma unroll
      for (int nt = 0; nt < 4; ++nt) scat128(Cs, w * 32 + rg * 16, lane, nt, cc[rg][nt]);
#pragma unroll
    for (int rg = 0; rg < 2; ++rg)
#pragma unroll
      for (int ks = 0; ks < 2; ++ks) {
        bf8v a = ldA128(Cs, w * 32 + rg * 16 + c16, ks * 32 + koff);
#pragma unroll
        for (int nt = 0; nt < 4; ++nt) {
          bf8v b = ldA128(Wuc, nt * 16 + c16, ks * 32 + koff);
          acc[rg][nt] = MFMA16(a, b, acc[rg][nt]);
        }
      }
    __syncthreads();
  }

  float w4[4];
#pragma unroll
  for (int nt = 0; nt < 4; ++nt) w4[nt] = qnw[nt * 16 + c16] * PS;
#pragma unroll
  for (int rg = 0; rg < 2; ++rg)
#pragma unroll
    for (int r = 0; r < 4; ++r) {
      float ss = 0.f;
#pragma unroll
      for (int nt = 0; nt < 4; ++nt) ss += acc[rg][nt][r] * acc[rg][nt][r];
      ss += __shfl_xor(ss, 1, 16); ss += __shfl_xor(ss, 2, 16);
      ss += __shfl_xor(ss, 4, 16); ss += __shfl_xor(ss, 8, 16);
      float inv = rsqrtf(ss * (1.f / 64.f) + EPS);
#pragma unroll
      for (int nt = 0; nt < 4; ++nt) acc[rg][nt][r] *= inv * w4[nt];
    }

#pragma unroll
  for (int rg = 0; rg < 2; ++rg)
#pragma unroll
    for (int nt = 0; nt < 4; ++nt) scat128(Cs, w * 32 + rg * 16, lane, nt, acc[rg][nt]);

  f4v qr[2][4];
#pragma unroll
  for (int rg = 0; rg < 2; ++rg)
#pragma unroll
    for (int nt = 0; nt < 4; ++nt) qr[rg][nt] = z4();
#pragma unroll
  for (int rg = 0; rg < 2; ++rg)
#pragma unroll
    for (int ks = 0; ks < 2; ++ks) {
      bf8v a = ldA128(Cs, w * 32 + rg * 16 + c16, ks * 32 + koff);
#pragma unroll
      for (int nt = 0; nt < 4; ++nt) {
        bf8v b = ldA128(&Wd[0][0], nt * 16 + c16, ks * 32 + koff);
        qr[rg][nt] = MFMA16(a, b, qr[rg][nt]);
      }
    }
#pragma unroll
  for (int rg = 0; rg < 2; ++rg)
#pragma unroll
    for (int nt = 0; nt < 4; ++nt) scat128(Xs, w * 32 + rg * 16, lane, nt, qr[rg][nt]);
  __syncthreads();

  short* qdst = qb + ((size_t)bh * T + t0) * 128;
#pragma unroll
  for (int p = 0; p < 4; ++p) {
    int ci = tid + p * 256;
    int r = ci >> 3, c = (ci & 7) << 3;
    *(bf8v*)(qdst + (size_t)r * 128 + c) =
        *(const bf8v*)((const char*)Cs + swz128(ci * 16));
    *(bf8v*)(qdst + (size_t)r * 128 + 64 + c) =
        *(const bf8v*)((const char*)Xs + swz128(ci * 16));
  }
}

// ---------------------------------------------------------------------------
// proj_kv v2 (unchanged from round 10)
// ---------------------------------------------------------------------------
__global__ __launch_bounds__(256) void proj_kv_mfma(
    const short* __restrict__ xb, const short* __restrict__ wb,
    const float* __restrict__ knw, short* __restrict__ kb, short* __restrict__ vtg) {
  __shared__ __attribute__((aligned(16))) short Xs[128 * 64];    // 16KB
  __shared__ __attribute__((aligned(16))) short Wd[2][64 * 64];  // 2x8KB
  __shared__ __attribute__((aligned(16))) short Wu[2][128 * 64]; // 2x16KB (-> Ko 32KB)
  __shared__ __attribute__((aligned(16))) short Cs[128 * 64];    // 16KB (-> Vt)

  const int tid = threadIdx.x, lane = tid & 63, w = tid >> 6;
  const int bh = blockIdx.y, t0 = blockIdx.x * 128;
  const int c16 = lane & 15;
  const int g4 = lane >> 4;
  const int koff = g4 << 3;
  const int rg4 = g4 << 2;

  auto stageWd = [&](int lc) {
    const char* src = (const char*)(wb + OFF_DKV + lc * 64 * 64);
    char* dst = (char*)&Wd[lc & 1][0];
#pragma unroll
    for (int p = 0; p < 2; ++p) {
      const int base = p * 256 + w * 64;
      gload_lds16(src + swz128((base + lane) * 16), dst + base * 16);
    }
  };
  auto stageWu = [&](int lc) {
    const char* src = (const char*)(wb + OFF_UKV + lc * 64);
    char* dst = (char*)&Wu[lc & 1][0];
#pragma unroll
    for (int p = 0; p < 4; ++p) {
      const int base = p * 256 + w * 64;
      const int lb = swz128((base + lane) * 16);
      gload_lds16(src + (size_t)(lb >> 7) * 2048 + (lb & 127), dst + base * 16);
    }
  };

  {
    const char* src = (const char*)(xb + ((size_t)bh * T + t0) * 64);
#pragma unroll
    for (int p = 0; p < 4; ++p) {
      const int base = p * 256 + w * 64;
      gload_lds16(src + swz128((base + lane) * 16), (char*)Xs + base * 16);
    }
  }
  stageWd(0);
  stageWu(0);
  __syncthreads();

  f4v acc[2][8];
#pragma unroll
  for (int rg = 0; rg < 2; ++rg)
#pragma unroll
    for (int nt = 0; nt < 8; ++nt) acc[rg][nt] = z4();

  for (int lc = 0; lc < 16; ++lc) {
    if (lc < 15) { stageWd(lc + 1); stageWu(lc + 1); }
    else {
      const char* src = (const char*)(wb + OFF_KR);
      char* dst = (char*)&Wd[0][0];
#pragma unroll
      for (int p = 0; p < 2; ++p) {
        const int base = p * 256 + w * 64;
        gload_lds16(src + swz128((base + lane) * 16), dst + base * 16);
      }
    }
    const short* Wdc = &Wd[lc & 1][0];
    const short* Wuc = &Wu[lc & 1][0];

    f4v cc[2][4];
#pragma unroll
    for (int rg = 0; rg < 2; ++rg)
#pragma unroll
      for (int nt = 0; nt < 4; ++nt) cc[rg][nt] = z4();
#pragma unroll
    for (int rg = 0; rg < 2; ++rg)
#pragma unroll
      for (int ks = 0; ks < 2; ++ks) {
        bf8v a = ldA128(Xs, w * 32 + rg * 16 + c16, ks * 32 + koff);
#pragma unroll
        for (int nt = 0; nt < 4; ++nt) {
          bf8v b = ldA128(Wdc, nt * 16 + c16, ks * 32 + koff);
          cc[rg][nt] = MFMA16(a, b, cc[rg][nt]);
        }
      }
#pragma unroll
    for (int rg = 0; rg < 2; ++rg)
#pragma unroll
      for (int nt = 0; nt < 4; ++nt) scat128(Cs, w * 32 + rg * 16, lane, nt, cc[rg][nt]);
#pragma unroll
    for (int rg = 0; rg < 2; ++rg)
#pragma unroll
      for (int ks = 0; ks < 2; ++ks) {
        bf8v a = ldA128(Cs, w * 32 + rg * 16 + c16, ks * 32 + koff);
#pragma unroll
        for (int nt = 0; nt < 8; ++nt) {
          bf8v b = ldA128(Wuc, nt * 16 + c16, ks * 32 + koff);
          acc[rg][nt] = MFMA16(a, b, acc[rg][nt]);
        }
      }
    __syncthreads();
  }

  float w4[4];
#pragma unroll
  for (int nt = 0; nt < 4; ++nt) w4[nt] = knw[nt * 16 + c16];
#pragma unroll
  for (int rg = 0; rg < 2; ++rg)
#pragma unroll
    for (int r = 0; r < 4; ++r) {
      float ss = 0.f;
#pragma unroll
      for (int nt = 0; nt < 4; ++nt) ss += acc[rg][nt][r] * acc[rg][nt][r];
      ss += __shfl_xor(ss, 1, 16); ss += __shfl_xor(ss, 2, 16);
      ss += __shfl_xor(ss, 4, 16); ss += __shfl_xor(ss, 8, 16);
      float inv = rsqrtf(ss * (1.f / 64.f) + EPS);
#pragma unroll
      for (int nt = 0; nt < 4; ++nt) acc[rg][nt][r] *= inv * w4[nt];
    }

  short* Ko = &Wu[0][0];
#pragma unroll
  for (int rg = 0; rg < 2; ++rg)
#pragma unroll
    for (int nt = 0; nt < 4; ++nt)
      scat256(Ko, w * 32 + rg * 16, lane, nt * 16 + c16, acc[rg][nt]);

#pragma unroll
  for (int rg = 0; rg < 2; ++rg)
#pragma unroll
    for (int nt = 0; nt < 4; ++nt) {
      const int d = nt * 16 + c16;
      const int tc0 = w * 32 + rg * 16 + rg4;
#pragma unroll
      for (int r = 0; r < 4; ++r)
        *(short*)((char*)Cs + swz256(d * 256 + (tc0 + r) * 2)) =
            f2bf(acc[rg][4 + nt][r]);
    }

  f4v kr[2][4];
#pragma unroll
  for (int rg = 0; rg < 2; ++rg)
#pragma unroll
    for (int nt = 0; nt < 4; ++nt) kr[rg][nt] = z4();
#pragma unroll
  for (int rg = 0; rg < 2; ++rg)
#pragma unroll
    for (int ks = 0; ks < 2; ++ks) {
      bf8v a = ldA128(Xs, w * 32 + rg * 16 + c16, ks * 32 + koff);
#pragma unroll
      for (int nt = 0; nt < 4; ++nt) {
        bf8v b = ldA128(&Wd[0][0], nt * 16 + c16, ks * 32 + koff);
        kr[rg][nt] = MFMA16(a, b, kr[rg][nt]);
      }
    }
#pragma unroll
  for (int rg = 0; rg < 2; ++rg)
#pragma unroll
    for (int nt = 0; nt < 4; ++nt)
      scat256(Ko, w * 32 + rg * 16, lane, 64 + nt * 16 + c16, kr[rg][nt]);
  __syncthreads();

  short* kdst = kb + ((size_t)bh * T + t0) * 128;
#pragma unroll
  for (int p = 0; p < 8; ++p) {
    int ci = tid + p * 256;
    int r = ci >> 4, c = (ci & 15) << 3;
    *(bf8v*)(kdst + (size_t)r * 128 + c) =
        *(const bf8v*)((const char*)Ko + swz256(ci * 16));
  }
#pragma unroll
  for (int p = 0; p < 4; ++p) {
    int ci = tid + p * 256;
    int d = ci >> 4, c = (ci & 15) << 3;
    *(bf8v*)(vtg + ((size_t)bh * 64 + d) * T + t0 + c) =
        *(const bf8v*)((const char*)Cs + swz256(ci * 16));
  }
}

// ---------------------------------------------------------------------------
// attn v8: occupancy attack. grid 1024 (one 64-row q-tile per block, largest
// qt dispatched first -> dynamic load balance), LDS 40KB (Ks[2]+Ps) -> 4
// blocks/CU = 16 waves/CU. V per-wave reg loads issued BEFORE the K
// global_load_lds each iteration, so the compiler's automatic V-wait is
// vmcnt(4) and leaves the K prefetch in flight. One HARD_BARRIER per tile.
// ---------------------------------------------------------------------------
__global__ __launch_bounds__(256, 4) void attn_mfma(
    const short* __restrict__ qb, const short* __restrict__ kb,
    const short* __restrict__ vtg, const short* __restrict__ wb,
    float* __restrict__ out) {
  __shared__ __attribute__((aligned(16))) short Ks[2][64 * 128]; // swz256, 16KB ea
  __shared__ __attribute__((aligned(16))) short Ps[64 * 64];     // swz128, 8KB

  const int tid = threadIdx.x, lane = tid & 63, w = tid >> 6;
  const int lin = blockIdx.x;            // [0,1024)
  const int qt  = 31 - (lin >> 5);       // largest work first in dispatch order
  const int inner = lin & 31;
  const int bh  = (inner & 7) + 8 * (inner >> 3); // XCD-clustered (4 bh/XCD)

  const int b = bh >> 4, h = bh & 15;
  const int c16 = lane & 15;
  const int g4 = lane >> 4;
  const int koff = g4 << 3;
  const int rg4 = g4 << 2;
  const int lbase = lane & 48;

  const short* kbh = kb + (size_t)bh * T * 128;
  const short* vbh = vtg + (size_t)bh * 64 * T;
  const int t0 = qt * 64;
  const int lrow = w * 16 + rg4;
  const int qglob = t0 + w * 16 + c16;

  // Q fragments (rows t0 + w*16 + c16, full k=128)
  bf8v aq[4];
  {
    const short* qsrc = qb + ((size_t)bh * T + t0 + w * 16 + c16) * 128;
#pragma unroll
    for (int ks = 0; ks < 4; ++ks) aq[ks] = *(const bf8v*)(qsrc + ks * 32 + koff);
  }

  auto stageK = [&](int jt, int buf) { // 4 gload_lds per wave
    const char* src = (const char*)(kbh + jt * 64 * 128);
    char* dst = (char*)&Ks[buf][0];
#pragma unroll
    for (int p = 0; p < 4; ++p) {
      const int base = p * 256 + w * 64;
      gload_lds16(src + swz256((base + lane) * 16), dst + base * 16);
    }
  };

  stageK(0, 0);
  asm volatile("s_waitcnt vmcnt(0)" ::: "memory");
  HARD_BARRIER();

  f4v ctx[4];
  float m = -INFINITY, l = 0.f;
#pragma unroll
  for (int nt = 0; nt < 4; ++nt) ctx[nt] = z4();

  for (int jt = 0; jt <= qt; ++jt) {
    const short* Kb = &Ks[jt & 1][0];
    const int j0 = jt * 64;
    const bool diag = (jt == qt);

    // V(jt) register loads FIRST (oldest in vmem queue -> compiler's wait for
    // them at PV is vmcnt(4), leaving the K prefetch below in flight)
    bf8v vb[2][4];
#pragma unroll
    for (int ks = 0; ks < 2; ++ks)
#pragma unroll
      for (int nt = 0; nt < 4; ++nt)
        vb[ks][nt] = *(const bf8v*)(vbh + (size_t)(nt * 16 + c16) * T +
                                    j0 + ks * 32 + koff);
    __builtin_amdgcn_sched_barrier(0); // pin V issues above the K issues

    // prefetch next K tile (last iter: restage current tile, dead buffer)
    stageK((jt < qt) ? jt + 1 : qt, (jt + 1) & 1);

    // Swapped QK^T: s = mfma(K, Q) -> s[nt][r] = S[kpos=j0+nt*16+rg4+r][qglob]
    f4v s[4];
#pragma unroll
    for (int nt = 0; nt < 4; ++nt) s[nt] = z4();
#pragma unroll
    for (int ks = 0; ks < 4; ++ks) {
#pragma unroll
      for (int nt = 0; nt < 4; ++nt) {
        bf8v bk = ldA256(Kb, nt * 16 + c16, ks * 32 + koff);
        s[nt] = MFMA16(bk, aq[ks], s[nt]); // A=K, B=Q
      }
    }

    if (diag) {
#pragma unroll
      for (int nt = 0; nt < 4; ++nt)
#pragma unroll
        for (int r = 0; r < 4; ++r)
          if (j0 + nt * 16 + rg4 + r > qglob) s[nt][r] = -INFINITY;
    }

    // row max: in-lane tree + 2 cross-group shfl
    f4v mnt;
#pragma unroll
    for (int r = 0; r < 4; ++r)
      mnt[r] = fmaxf(fmaxf(s[0][r], s[1][r]), fmaxf(s[2][r], s[3][r]));
    float mx = fmaxf(fmaxf(mnt[0], mnt[1]), fmaxf(mnt[2], mnt[3]));
    mx = fmaxf(mx, __shfl_xor(mx, 16));
    mx = fmaxf(mx, __shfl_xor(mx, 32));

    // defer-max rescale (THR=8, exp2 domain)
    if (__any(mx - m > 8.f)) {
      const float mn  = fmaxf(m, mx);
      const float scl = __builtin_amdgcn_exp2f(m - mn);
      l *= scl; m = mn;
      float sr[4];
#pragma unroll
      for (int r = 0; r < 4; ++r) sr[r] = __shfl(scl, lbase + rg4 + r);
#pragma unroll
      for (int nt = 0; nt < 4; ++nt)
#pragma unroll
        for (int r = 0; r < 4; ++r) ctx[nt][r] *= sr[r];
    }

    // p = exp2(s - m); in-lane sum + 2 shfl
#pragma unroll
    for (int nt = 0; nt < 4; ++nt)
#pragma unroll
      for (int r = 0; r < 4; ++r)
        s[nt][r] = __builtin_amdgcn_exp2f(s[nt][r] - m);
    f4v sv = s[0] + s[1] + s[2] + s[3];
    float rs = (sv[0] + sv[1]) + (sv[2] + sv[3]);
    rs += __shfl_xor(rs, 16);
    rs += __shfl_xor(rs, 32);
    l += rs;

    // P -> LDS: 4x ds_write_b64, hw cvt_pk pairs (wave-private rows)
    {
      char* prow = (char*)Ps;
      const int rbase = (w * 16 + c16) * 128 + koff;
#pragma unroll
      for (int nt = 0; nt < 4; ++nt) {
        __hip_bfloat162 h0 = __float22bfloat162_rn(make_float2(s[nt][0], s[nt][1]));
        __hip_bfloat162 h1 = __float22bfloat162_rn(make_float2(s[nt][2], s[nt][3]));
        uint2 d;
        d.x = *(unsigned int*)&h0;
        d.y = *(unsigned int*)&h1;
        *(uint2*)(prow + swz128(rbase + nt * 32)) = d;
      }
    }

    // PV: compiler inserts vmcnt(4) for vb (V oldest), K prefetch stays in flight
#pragma unroll
    for (int ks = 0; ks < 2; ++ks) {
      bf8v pa = ldA128(Ps, w * 16 + c16, ks * 32 + koff);
#pragma unroll
      for (int nt = 0; nt < 4; ++nt) ctx[nt] = MFMA16(pa, vb[ks][nt], ctx[nt]);
    }

    // drain own K(jt+1) (issued ~2000cy ago, cheap) + barrier: all waves'
    // K(jt+1) landed before next QK, and WAR on Ks[jt&1] for next stage
    asm volatile("s_waitcnt vmcnt(0)" ::: "memory");
    HARD_BARRIER();
  }

  // epilogue: ctx/l -> Ps, out = ctx @ W_O^T (W_O frags loaded here, not in loop)
  float linv[4];
#pragma unroll
  for (int r = 0; r < 4; ++r) linv[r] = 1.0f / __shfl(l, lbase + rg4 + r);
  f4v cn[4];
#pragma unroll
  for (int nt = 0; nt < 4; ++nt)
#pragma unroll
    for (int r = 0; r < 4; ++r) cn[nt][r] = ctx[nt][r] * linv[r];
#pragma unroll
  for (int nt = 0; nt < 4; ++nt) scat128(Ps, w * 16, lane, nt, cn[nt]);

  f4v o[4];
#pragma unroll
  for (int nt = 0; nt < 4; ++nt) o[nt] = z4();
#pragma unroll
  for (int ks = 0; ks < 2; ++ks) {
    bf8v pa = ldA128(Ps, w * 16 + c16, ks * 32 + koff);
#pragma unroll
    for (int nt = 0; nt < 4; ++nt) {
      bf8v bw = *(const bf8v*)(wb + OFF_O + (size_t)(nt * 16 + c16) * 64 +
                               ks * 32 + koff);
      o[nt] = MFMA16(pa, bw, o[nt]);
    }
  }

  float* obase = out + (size_t)b * T * 1024 + h * 64;
#pragma unroll
  for (int nt = 0; nt < 4; ++nt) {
#pragma unroll
    for (int r = 0; r < 4; ++r)
      obase[(size_t)(t0 + lrow + r) * 1024 + nt * 16 + c16] = o[nt][r];
  }
}

} // namespace

extern "C" void kernel_launch(void* const* d_in, const int* in_sizes, int n_in,
                              void* d_out, int out_size, void* d_ws, size_t ws_size,
                              hipStream_t stream) {
  (void)in_sizes; (void)n_in; (void)out_size; (void)ws_size;
  const float* x     = (const float*)d_in[0];
  const float* W_DQ  = (const float*)d_in[1];
  const float* W_UQ  = (const float*)d_in[2];
  const float* W_DKV = (const float*)d_in[3];
  const float* W_UKV = (const float*)d_in[4];
  const float* W_QR  = (const float*)d_in[5];
  const float* W_KR  = (const float*)d_in[6];
  const float* W_O   = (const float*)d_in[7];
  const float* qnw   = (const float*)d_in[8];
  const float* knw   = (const float*)d_in[9];
  float* out = (float*)d_out;

  short* ws = (short*)d_ws;
  short* xb  = ws;                          // 4,194,304
  short* qb  = ws + (size_t)4194304;        // 8,388,608
  short* kb  = ws + (size_t)12582912;       // 8,388,608
  short* vtg = ws + (size_t)20971520;       // 4,194,304
  short* wb  = ws + (size_t)25165824;       // 274,432

  cvt_x_kernel<<<4096, 256, 0, stream>>>(x, xb);
  cvt_w_kernel<<<W_TOTAL / 256, 256, 0, stream>>>(W_DQ, W_UQ, W_DKV, W_UKV,
                                                  W_QR, W_KR, W_O, wb);
  dim3 pgrid(T / 128, 32); // 128-row tiles
  proj_q_mfma<<<pgrid, 256, 0, stream>>>(xb, wb, qnw, qb);
  proj_kv_mfma<<<pgrid, 256, 0, stream>>>(xb, wb, knw, kb, vtg);
  attn_mfma<<<1024, 256, 0, stream>>>(qb, kb, vtg, wb, out);
}

// Round 12
// 157.144 us; speedup vs baseline: 1.1481x; 1.1481x over previous
//
#include <hip/hip_runtime.h>
#include <hip/hip_bf16.h>
#include <math.h>

namespace {

constexpr int T  = 2048;
constexpr int HD = 64;
constexpr float EPS = 1.1920929e-07f;
// SCALE * log2(e), folded into q at proj_q write time -> attn softmax runs in exp2 domain
constexpr float PS = 0.125f * 1.44269504f;

// bf16 weight pool offsets (in elements)
constexpr int OFF_DQ  = 0;       // 512*64
constexpr int OFF_UQ  = 32768;   // 64*512
constexpr int OFF_DKV = 65536;   // 1024*64
constexpr int OFF_UKV = 131072;  // 128*1024
constexpr int OFF_QR  = 262144;  // 64*64
constexpr int OFF_KR  = 266240;  // 64*64
constexpr int OFF_O   = 270336;  // 64*64
constexpr int W_TOTAL = 274432;

typedef __attribute__((ext_vector_type(8))) short bf8v;  // 8 bf16 (4 VGPR)
typedef __attribute__((ext_vector_type(4))) float f4v;   // MFMA C/D

#define MFMA16(a, b, c) __builtin_amdgcn_mfma_f32_16x16x32_bf16((a), (b), (c), 0, 0, 0)

// full-strength barrier for raw s_barrier use (rule #18 class): compiler
// memory fences both sides so gload_lds issues can't be hoisted across.
#define HARD_BARRIER()                                   \
  do {                                                   \
    asm volatile("" ::: "memory");                       \
    __builtin_amdgcn_s_barrier();                        \
    asm volatile("" ::: "memory");                       \
    __builtin_amdgcn_sched_barrier(0);                   \
  } while (0)

__device__ __forceinline__ short f2bf(float f) {
  union { float f; unsigned u; } v; v.f = f;
  unsigned r = v.u + 0x7FFFu + ((v.u >> 16) & 1u); // RNE
  return (short)(r >> 16);
}

__device__ __forceinline__ f4v z4() { f4v z = {0.f, 0.f, 0.f, 0.f}; return z; }

// XOR swizzles: spread row-strided b128 accesses across banks (m214 pattern)
__device__ __forceinline__ int swz128(int b) { return b ^ (((b >> 7) & 7) << 4); }
__device__ __forceinline__ int swz256(int b) { return b ^ (((b >> 8) & 7) << 4); }

__device__ __forceinline__ bf8v ldA128(const short* lds, int row, int k) {
  return *(const bf8v*)((const char*)lds + swz128(row * 128 + k * 2));
}
__device__ __forceinline__ bf8v ldA256(const short* lds, int row, int k) {
  return *(const bf8v*)((const char*)lds + swz256(row * 256 + k * 2));
}

// scatter a 16x16 D-fragment (col=lane&15, row=(lane>>4)*4+r) as bf16 into LDS
__device__ __forceinline__ void scat128(short* lds, int row0, int lane, int nt, f4v v) {
  int col = nt * 16 + (lane & 15);
  int r0 = row0 + ((lane >> 4) << 2);
#pragma unroll
  for (int r = 0; r < 4; ++r)
    *(short*)((char*)lds + swz128((r0 + r) * 128 + col * 2)) = f2bf(v[r]);
}
__device__ __forceinline__ void scat256(short* lds, int row0, int lane, int col, f4v v) {
  int r0 = row0 + ((lane >> 4) << 2);
#pragma unroll
  for (int r = 0; r < 4; ++r)
    *(short*)((char*)lds + swz256((r0 + r) * 256 + col * 2)) = f2bf(v[r]);
}

// async global->LDS, 16B per lane; LDS dest wave-uniform base + lane*16
__device__ __forceinline__ void gload_lds16(const void* g, void* l) {
  __builtin_amdgcn_global_load_lds(
      (const __attribute__((address_space(1))) void*)g,
      (__attribute__((address_space(3))) void*)l, 16, 0, 0);
}

// ---------------------------------------------------------------------------
// conversions
// ---------------------------------------------------------------------------
__global__ __launch_bounds__(256) void cvt_x_kernel(const float* __restrict__ x,
                                                    short* __restrict__ xb) {
  int i = (blockIdx.x * 256 + threadIdx.x) * 4; // over x linear (B,T,D)
  float4 v = *(const float4*)(x + i);
  int d = i & 1023, t = (i >> 10) & 2047, b = i >> 21;
  int h = d >> 6, dd = d & 63;
  short4 o;
  o.x = f2bf(v.x); o.y = f2bf(v.y); o.z = f2bf(v.z); o.w = f2bf(v.w);
  *(short4*)(xb + ((((size_t)b * 16 + h) * T + t) * 64 + dd)) = o;
}

__global__ __launch_bounds__(256) void cvt_w_kernel(
    const float* __restrict__ W_DQ, const float* __restrict__ W_UQ,
    const float* __restrict__ W_DKV, const float* __restrict__ W_UKV,
    const float* __restrict__ W_QR, const float* __restrict__ W_KR,
    const float* __restrict__ W_O, short* __restrict__ wb) {
  int i = blockIdx.x * 256 + threadIdx.x;
  const float* src; int off;
  if      (i < 32768)  { src = W_DQ;  off = 0; }
  else if (i < 65536)  { src = W_UQ;  off = 32768; }
  else if (i < 131072) { src = W_DKV; off = 65536; }
  else if (i < 262144) { src = W_UKV; off = 131072; }
  else if (i < 266240) { src = W_QR;  off = 262144; }
  else if (i < 270336) { src = W_KR;  off = 266240; }
  else                 { src = W_O;   off = 270336; }
  wb[i] = f2bf(src[i - off]);
}

// ---------------------------------------------------------------------------
// proj_q v2 (unchanged; __syncthreads-based, airtight)
// ---------------------------------------------------------------------------
__global__ __launch_bounds__(256) void proj_q_mfma(
    const short* __restrict__ xb, const short* __restrict__ wb,
    const float* __restrict__ qnw, short* __restrict__ qb) {
  __shared__ __attribute__((aligned(16))) short Xs[128 * 64];   // 16KB
  __shared__ __attribute__((aligned(16))) short Wd[2][64 * 64]; // 2x8KB
  __shared__ __attribute__((aligned(16))) short Wu[2][64 * 64]; // 2x8KB
  __shared__ __attribute__((aligned(16))) short Cs[128 * 64];   // 16KB

  const int tid = threadIdx.x, lane = tid & 63, w = tid >> 6;
  const int bh = blockIdx.y, t0 = blockIdx.x * 128;
  const int c16 = lane & 15;
  const int koff = (lane >> 4) << 3;

  auto stageWd = [&](int lc) {
    const char* src = (const char*)(wb + OFF_DQ + lc * 64 * 64);
    char* dst = (char*)&Wd[lc & 1][0];
#pragma unroll
    for (int p = 0; p < 2; ++p) {
      const int base = p * 256 + w * 64;
      gload_lds16(src + swz128((base + lane) * 16), dst + base * 16);
    }
  };
  auto stageWu = [&](int lc) {
    const char* src = (const char*)(wb + OFF_UQ + lc * 64);
    char* dst = (char*)&Wu[lc & 1][0];
#pragma unroll
    for (int p = 0; p < 2; ++p) {
      const int base = p * 256 + w * 64;
      const int lb = swz128((base + lane) * 16);
      gload_lds16(src + (size_t)(lb >> 7) * 1024 + (lb & 127), dst + base * 16);
    }
  };

  {
    const char* src = (const char*)(xb + ((size_t)bh * T + t0) * 64);
#pragma unroll
    for (int p = 0; p < 4; ++p) {
      const int base = p * 256 + w * 64;
      gload_lds16(src + swz128((base + lane) * 16), (char*)Xs + base * 16);
    }
  }
  stageWd(0);
  stageWu(0);
  __syncthreads();

  f4v acc[2][4];
#pragma unroll
  for (int rg = 0; rg < 2; ++rg)
#pragma unroll
    for (int nt = 0; nt < 4; ++nt) acc[rg][nt] = z4();

  for (int lc = 0; lc < 8; ++lc) {
    if (lc < 7) { stageWd(lc + 1); stageWu(lc + 1); }
    else {
      const char* src = (const char*)(wb + OFF_QR);
      char* dst = (char*)&Wd[0][0];
#pragma unroll
      for (int p = 0; p < 2; ++p) {
        const int base = p * 256 + w * 64;
        gload_lds16(src + swz128((base + lane) * 16), dst + base * 16);
      }
    }
    const short* Wdc = &Wd[lc & 1][0];
    const short* Wuc = &Wu[lc & 1][0];

    f4v cc[2][4];
#pragma unroll
    for (int rg = 0; rg < 2; ++rg)
#pragma unroll
      for (int nt = 0; nt < 4; ++nt) cc[rg][nt] = z4();
#pragma unroll
    for (int rg = 0; rg < 2; ++rg)
#pragma unroll
      for (int ks = 0; ks < 2; ++ks) {
        bf8v a = ldA128(Xs, w * 32 + rg * 16 + c16, ks * 32 + koff);
#pragma unroll
        for (int nt = 0; nt < 4; ++nt) {
          bf8v b = ldA128(Wdc, nt * 16 + c16, ks * 32 + koff);
          cc[rg][nt] = MFMA16(a, b, cc[rg][nt]);
        }
      }
#pragma unroll
    for (int rg = 0; rg < 2; ++rg)
#pragma unroll
      for (int nt = 0; nt < 4; ++nt) scat128(Cs, w * 32 + rg * 16, lane, nt, cc[rg][nt]);
#pragma unroll
    for (int rg = 0; rg < 2; ++rg)
#pragma unroll
      for (int ks = 0; ks < 2; ++ks) {
        bf8v a = ldA128(Cs, w * 32 + rg * 16 + c16, ks * 32 + koff);
#pragma unroll
        for (int nt = 0; nt < 4; ++nt) {
          bf8v b = ldA128(Wuc, nt * 16 + c16, ks * 32 + koff);
          acc[rg][nt] = MFMA16(a, b, acc[rg][nt]);
        }
      }
    __syncthreads();
  }

  float w4[4];
#pragma unroll
  for (int nt = 0; nt < 4; ++nt) w4[nt] = qnw[nt * 16 + c16] * PS;
#pragma unroll
  for (int rg = 0; rg < 2; ++rg)
#pragma unroll
    for (int r = 0; r < 4; ++r) {
      float ss = 0.f;
#pragma unroll
      for (int nt = 0; nt < 4; ++nt) ss += acc[rg][nt][r] * acc[rg][nt][r];
      ss += __shfl_xor(ss, 1, 16); ss += __shfl_xor(ss, 2, 16);
      ss += __shfl_xor(ss, 4, 16); ss += __shfl_xor(ss, 8, 16);
      float inv = rsqrtf(ss * (1.f / 64.f) + EPS);
#pragma unroll
      for (int nt = 0; nt < 4; ++nt) acc[rg][nt][r] *= inv * w4[nt];
    }

#pragma unroll
  for (int rg = 0; rg < 2; ++rg)
#pragma unroll
    for (int nt = 0; nt < 4; ++nt) scat128(Cs, w * 32 + rg * 16, lane, nt, acc[rg][nt]);

  f4v qr[2][4];
#pragma unroll
  for (int rg = 0; rg < 2; ++rg)
#pragma unroll
    for (int nt = 0; nt < 4; ++nt) qr[rg][nt] = z4();
#pragma unroll
  for (int rg = 0; rg < 2; ++rg)
#pragma unroll
    for (int ks = 0; ks < 2; ++ks) {
      bf8v a = ldA128(Cs, w * 32 + rg * 16 + c16, ks * 32 + koff);
#pragma unroll
      for (int nt = 0; nt < 4; ++nt) {
        bf8v b = ldA128(&Wd[0][0], nt * 16 + c16, ks * 32 + koff);
        qr[rg][nt] = MFMA16(a, b, qr[rg][nt]);
      }
    }
#pragma unroll
  for (int rg = 0; rg < 2; ++rg)
#pragma unroll
    for (int nt = 0; nt < 4; ++nt) scat128(Xs, w * 32 + rg * 16, lane, nt, qr[rg][nt]);
  __syncthreads();

  short* qdst = qb + ((size_t)bh * T + t0) * 128;
#pragma unroll
  for (int p = 0; p < 4; ++p) {
    int ci = tid + p * 256;
    int r = ci >> 3, c = (ci & 7) << 3;
    *(bf8v*)(qdst + (size_t)r * 128 + c) =
        *(const bf8v*)((const char*)Cs + swz128(ci * 16));
    *(bf8v*)(qdst + (size_t)r * 128 + 64 + c) =
        *(const bf8v*)((const char*)Xs + swz128(ci * 16));
  }
}

// ---------------------------------------------------------------------------
// proj_kv v2 (unchanged)
// ---------------------------------------------------------------------------
__global__ __launch_bounds__(256) void proj_kv_mfma(
    const short* __restrict__ xb, const short* __restrict__ wb,
    const float* __restrict__ knw, short* __restrict__ kb, short* __restrict__ vtg) {
  __shared__ __attribute__((aligned(16))) short Xs[128 * 64];    // 16KB
  __shared__ __attribute__((aligned(16))) short Wd[2][64 * 64];  // 2x8KB
  __shared__ __attribute__((aligned(16))) short Wu[2][128 * 64]; // 2x16KB (-> Ko 32KB)
  __shared__ __attribute__((aligned(16))) short Cs[128 * 64];    // 16KB (-> Vt)

  const int tid = threadIdx.x, lane = tid & 63, w = tid >> 6;
  const int bh = blockIdx.y, t0 = blockIdx.x * 128;
  const int c16 = lane & 15;
  const int g4 = lane >> 4;
  const int koff = g4 << 3;
  const int rg4 = g4 << 2;

  auto stageWd = [&](int lc) {
    const char* src = (const char*)(wb + OFF_DKV + lc * 64 * 64);
    char* dst = (char*)&Wd[lc & 1][0];
#pragma unroll
    for (int p = 0; p < 2; ++p) {
      const int base = p * 256 + w * 64;
      gload_lds16(src + swz128((base + lane) * 16), dst + base * 16);
    }
  };
  auto stageWu = [&](int lc) {
    const char* src = (const char*)(wb + OFF_UKV + lc * 64);
    char* dst = (char*)&Wu[lc & 1][0];
#pragma unroll
    for (int p = 0; p < 4; ++p) {
      const int base = p * 256 + w * 64;
      const int lb = swz128((base + lane) * 16);
      gload_lds16(src + (size_t)(lb >> 7) * 2048 + (lb & 127), dst + base * 16);
    }
  };

  {
    const char* src = (const char*)(xb + ((size_t)bh * T + t0) * 64);
#pragma unroll
    for (int p = 0; p < 4; ++p) {
      const int base = p * 256 + w * 64;
      gload_lds16(src + swz128((base + lane) * 16), (char*)Xs + base * 16);
    }
  }
  stageWd(0);
  stageWu(0);
  __syncthreads();

  f4v acc[2][8];
#pragma unroll
  for (int rg = 0; rg < 2; ++rg)
#pragma unroll
    for (int nt = 0; nt < 8; ++nt) acc[rg][nt] = z4();

  for (int lc = 0; lc < 16; ++lc) {
    if (lc < 15) { stageWd(lc + 1); stageWu(lc + 1); }
    else {
      const char* src = (const char*)(wb + OFF_KR);
      char* dst = (char*)&Wd[0][0];
#pragma unroll
      for (int p = 0; p < 2; ++p) {
        const int base = p * 256 + w * 64;
        gload_lds16(src + swz128((base + lane) * 16), dst + base * 16);
      }
    }
    const short* Wdc = &Wd[lc & 1][0];
    const short* Wuc = &Wu[lc & 1][0];

    f4v cc[2][4];
#pragma unroll
    for (int rg = 0; rg < 2; ++rg)
#pragma unroll
      for (int nt = 0; nt < 4; ++nt) cc[rg][nt] = z4();
#pragma unroll
    for (int rg = 0; rg < 2; ++rg)
#pragma unroll
      for (int ks = 0; ks < 2; ++ks) {
        bf8v a = ldA128(Xs, w * 32 + rg * 16 + c16, ks * 32 + koff);
#pragma unroll
        for (int nt = 0; nt < 4; ++nt) {
          bf8v b = ldA128(Wdc, nt * 16 + c16, ks * 32 + koff);
          cc[rg][nt] = MFMA16(a, b, cc[rg][nt]);
        }
      }
#pragma unroll
    for (int rg = 0; rg < 2; ++rg)
#pragma unroll
      for (int nt = 0; nt < 4; ++nt) scat128(Cs, w * 32 + rg * 16, lane, nt, cc[rg][nt]);
#pragma unroll
    for (int rg = 0; rg < 2; ++rg)
#pragma unroll
      for (int ks = 0; ks < 2; ++ks) {
        bf8v a = ldA128(Cs, w * 32 + rg * 16 + c16, ks * 32 + koff);
#pragma unroll
        for (int nt = 0; nt < 8; ++nt) {
          bf8v b = ldA128(Wuc, nt * 16 + c16, ks * 32 + koff);
          acc[rg][nt] = MFMA16(a, b, acc[rg][nt]);
        }
      }
    __syncthreads();
  }

  float w4[4];
#pragma unroll
  for (int nt = 0; nt < 4; ++nt) w4[nt] = knw[nt * 16 + c16];
#pragma unroll
  for (int rg = 0; rg < 2; ++rg)
#pragma unroll
    for (int r = 0; r < 4; ++r) {
      float ss = 0.f;
#pragma unroll
      for (int nt = 0; nt < 4; ++nt) ss += acc[rg][nt][r] * acc[rg][nt][r];
      ss += __shfl_xor(ss, 1, 16); ss += __shfl_xor(ss, 2, 16);
      ss += __shfl_xor(ss, 4, 16); ss += __shfl_xor(ss, 8, 16);
      float inv = rsqrtf(ss * (1.f / 64.f) + EPS);
#pragma unroll
      for (int nt = 0; nt < 4; ++nt) acc[rg][nt][r] *= inv * w4[nt];
    }

  short* Ko = &Wu[0][0];
#pragma unroll
  for (int rg = 0; rg < 2; ++rg)
#pragma unroll
    for (int nt = 0; nt < 4; ++nt)
      scat256(Ko, w * 32 + rg * 16, lane, nt * 16 + c16, acc[rg][nt]);

#pragma unroll
  for (int rg = 0; rg < 2; ++rg)
#pragma unroll
    for (int nt = 0; nt < 4; ++nt) {
      const int d = nt * 16 + c16;
      const int tc0 = w * 32 + rg * 16 + rg4;
#pragma unroll
      for (int r = 0; r < 4; ++r)
        *(short*)((char*)Cs + swz256(d * 256 + (tc0 + r) * 2)) =
            f2bf(acc[rg][4 + nt][r]);
    }

  f4v kr[2][4];
#pragma unroll
  for (int rg = 0; rg < 2; ++rg)
#pragma unroll
    for (int nt = 0; nt < 4; ++nt) kr[rg][nt] = z4();
#pragma unroll
  for (int rg = 0; rg < 2; ++rg)
#pragma unroll
    for (int ks = 0; ks < 2; ++ks) {
      bf8v a = ldA128(Xs, w * 32 + rg * 16 + c16, ks * 32 + koff);
#pragma unroll
      for (int nt = 0; nt < 4; ++nt) {
        bf8v b = ldA128(&Wd[0][0], nt * 16 + c16, ks * 32 + koff);
        kr[rg][nt] = MFMA16(a, b, kr[rg][nt]);
      }
    }
#pragma unroll
  for (int rg = 0; rg < 2; ++rg)
#pragma unroll
    for (int nt = 0; nt < 4; ++nt)
      scat256(Ko, w * 32 + rg * 16, lane, 64 + nt * 16 + c16, kr[rg][nt]);
  __syncthreads();

  short* kdst = kb + ((size_t)bh * T + t0) * 128;
#pragma unroll
  for (int p = 0; p < 8; ++p) {
    int ci = tid + p * 256;
    int r = ci >> 4, c = (ci & 15) << 3;
    *(bf8v*)(kdst + (size_t)r * 128 + c) =
        *(const bf8v*)((const char*)Ko + swz256(ci * 16));
  }
#pragma unroll
  for (int p = 0; p < 4; ++p) {
    int ci = tid + p * 256;
    int d = ci >> 4, c = (ci & 15) << 3;
    *(bf8v*)(vtg + ((size_t)bh * 64 + d) * T + t0 + c) =
        *(const bf8v*)((const char*)Cs + swz256(ci * 16));
  }
}

// ---------------------------------------------------------------------------
// attn v8b: v8 with (1) NO min-waves clamp (VGPR back to natural ~110 — the
// round-11 regression was launch_bounds(256,4) -> 64 VGPRs -> scratch spills,
// +13MB WRITE_SIZE) and (2) statically CU-balanced qt assignment: with 1024
// resident blocks and block->CU ~ lin%256, the 4 residents of CU c have
// g = c>>5 + {0,8,16,24}; qt(g) chosen so each CU's 4 qts sum to 62.
// LDS 40KB (Ks[2]+Ps) -> 4 blocks/CU = 16 waves/CU.
// ---------------------------------------------------------------------------
__global__ __launch_bounds__(256) void attn_mfma(
    const short* __restrict__ qb, const short* __restrict__ kb,
    const short* __restrict__ vtg, const short* __restrict__ wb,
    float* __restrict__ out) {
  __shared__ __attribute__((aligned(16))) short Ks[2][64 * 128]; // swz256, 16KB ea
  __shared__ __attribute__((aligned(16))) short Ps[64 * 64];     // swz128, 8KB

  const int tid = threadIdx.x, lane = tid & 63, w = tid >> 6;
  const int lin = blockIdx.x;            // [0,1024)
  const int g = lin >> 5;                // 32 qt-groups of 32 blocks
  // per-CU balanced qt permutation: qt(g)+qt(g+8)+qt(g+16)+qt(g+24) = 62
  const int qt = (g < 8) ? 31 - g : (g < 16) ? g - 8 : (g < 24) ? 39 - g : g - 16;
  const int inner = lin & 31;
  const int bh = (inner & 7) + 8 * (inner >> 3); // XCD-clustered (4 bh/XCD)

  const int b = bh >> 4, h = bh & 15;
  const int c16 = lane & 15;
  const int g4 = lane >> 4;
  const int koff = g4 << 3;
  const int rg4 = g4 << 2;
  const int lbase = lane & 48;

  const short* kbh = kb + (size_t)bh * T * 128;
  const short* vbh = vtg + (size_t)bh * 64 * T;
  const int t0 = qt * 64;
  const int lrow = w * 16 + rg4;
  const int qglob = t0 + w * 16 + c16;

  // Q fragments (rows t0 + w*16 + c16, full k=128)
  bf8v aq[4];
  {
    const short* qsrc = qb + ((size_t)bh * T + t0 + w * 16 + c16) * 128;
#pragma unroll
    for (int ks = 0; ks < 4; ++ks) aq[ks] = *(const bf8v*)(qsrc + ks * 32 + koff);
  }

  auto stageK = [&](int jt, int buf) { // 4 gload_lds per wave
    const char* src = (const char*)(kbh + jt * 64 * 128);
    char* dst = (char*)&Ks[buf][0];
#pragma unroll
    for (int p = 0; p < 4; ++p) {
      const int base = p * 256 + w * 64;
      gload_lds16(src + swz256((base + lane) * 16), dst + base * 16);
    }
  };

  stageK(0, 0);
  asm volatile("s_waitcnt vmcnt(0)" ::: "memory");
  HARD_BARRIER();

  f4v ctx[4];
  float m = -INFINITY, l = 0.f;
#pragma unroll
  for (int nt = 0; nt < 4; ++nt) ctx[nt] = z4();

  for (int jt = 0; jt <= qt; ++jt) {
    const short* Kb = &Ks[jt & 1][0];
    const int j0 = jt * 64;
    const bool diag = (jt == qt);

    // V(jt) register loads FIRST (oldest in vmem queue -> compiler's wait for
    // them at PV is vmcnt(4), leaving the K prefetch below in flight)
    bf8v vb[2][4];
#pragma unroll
    for (int ks = 0; ks < 2; ++ks)
#pragma unroll
      for (int nt = 0; nt < 4; ++nt)
        vb[ks][nt] = *(const bf8v*)(vbh + (size_t)(nt * 16 + c16) * T +
                                    j0 + ks * 32 + koff);
    __builtin_amdgcn_sched_barrier(0); // pin V issues above the K issues

    // prefetch next K tile (last iter: restage current tile, dead buffer)
    stageK((jt < qt) ? jt + 1 : qt, (jt + 1) & 1);

    // Swapped QK^T: s = mfma(K, Q) -> s[nt][r] = S[kpos=j0+nt*16+rg4+r][qglob]
    f4v s[4];
#pragma unroll
    for (int nt = 0; nt < 4; ++nt) s[nt] = z4();
#pragma unroll
    for (int ks = 0; ks < 4; ++ks) {
#pragma unroll
      for (int nt = 0; nt < 4; ++nt) {
        bf8v bk = ldA256(Kb, nt * 16 + c16, ks * 32 + koff);
        s[nt] = MFMA16(bk, aq[ks], s[nt]); // A=K, B=Q
      }
    }

    if (diag) {
#pragma unroll
      for (int nt = 0; nt < 4; ++nt)
#pragma unroll
        for (int r = 0; r < 4; ++r)
          if (j0 + nt * 16 + rg4 + r > qglob) s[nt][r] = -INFINITY;
    }

    // row max: in-lane tree + 2 cross-group shfl
    f4v mnt;
#pragma unroll
    for (int r = 0; r < 4; ++r)
      mnt[r] = fmaxf(fmaxf(s[0][r], s[1][r]), fmaxf(s[2][r], s[3][r]));
    float mx = fmaxf(fmaxf(mnt[0], mnt[1]), fmaxf(mnt[2], mnt[3]));
    mx = fmaxf(mx, __shfl_xor(mx, 16));
    mx = fmaxf(mx, __shfl_xor(mx, 32));

    // defer-max rescale (THR=8, exp2 domain)
    if (__any(mx - m > 8.f)) {
      const float mn  = fmaxf(m, mx);
      const float scl = __builtin_amdgcn_exp2f(m - mn);
      l *= scl; m = mn;
      float sr[4];
#pragma unroll
      for (int r = 0; r < 4; ++r) sr[r] = __shfl(scl, lbase + rg4 + r);
#pragma unroll
      for (int nt = 0; nt < 4; ++nt)
#pragma unroll
        for (int r = 0; r < 4; ++r) ctx[nt][r] *= sr[r];
    }

    // p = exp2(s - m); in-lane sum + 2 shfl
#pragma unroll
    for (int nt = 0; nt < 4; ++nt)
#pragma unroll
      for (int r = 0; r < 4; ++r)
        s[nt][r] = __builtin_amdgcn_exp2f(s[nt][r] - m);
    f4v sv = s[0] + s[1] + s[2] + s[3];
    float rs = (sv[0] + sv[1]) + (sv[2] + sv[3]);
    rs += __shfl_xor(rs, 16);
    rs += __shfl_xor(rs, 32);
    l += rs;

    // P -> LDS: 4x ds_write_b64, hw cvt_pk pairs (wave-private rows)
    {
      char* prow = (char*)Ps;
      const int rbase = (w * 16 + c16) * 128 + koff;
#pragma unroll
      for (int nt = 0; nt < 4; ++nt) {
        __hip_bfloat162 h0 = __float22bfloat162_rn(make_float2(s[nt][0], s[nt][1]));
        __hip_bfloat162 h1 = __float22bfloat162_rn(make_float2(s[nt][2], s[nt][3]));
        uint2 d;
        d.x = *(unsigned int*)&h0;
        d.y = *(unsigned int*)&h1;
        *(uint2*)(prow + swz128(rbase + nt * 32)) = d;
      }
    }

    // PV: compiler inserts vmcnt(4) for vb (V oldest), K prefetch stays in flight
#pragma unroll
    for (int ks = 0; ks < 2; ++ks) {
      bf8v pa = ldA128(Ps, w * 16 + c16, ks * 32 + koff);
#pragma unroll
      for (int nt = 0; nt < 4; ++nt) ctx[nt] = MFMA16(pa, vb[ks][nt], ctx[nt]);
    }

    // drain own K(jt+1) (issued before QK, mostly landed) + barrier: all
    // waves' K(jt+1) landed before next QK, and WAR on Ks[jt&1]
    asm volatile("s_waitcnt vmcnt(0)" ::: "memory");
    HARD_BARRIER();
  }

  // epilogue: ctx/l -> Ps, out = ctx @ W_O^T (W_O frags loaded here, not in loop)
  float linv[4];
#pragma unroll
  for (int r = 0; r < 4; ++r) linv[r] = 1.0f / __shfl(l, lbase + rg4 + r);
  f4v cn[4];
#pragma unroll
  for (int nt = 0; nt < 4; ++nt)
#pragma unroll
    for (int r = 0; r < 4; ++r) cn[nt][r] = ctx[nt][r] * linv[r];
#pragma unroll
  for (int nt = 0; nt < 4; ++nt) scat128(Ps, w * 16, lane, nt, cn[nt]);

  f4v o[4];
#pragma unroll
  for (int nt = 0; nt < 4; ++nt) o[nt] = z4();
#pragma unroll
  for (int ks = 0; ks < 2; ++ks) {
    bf8v pa = ldA128(Ps, w * 16 + c16, ks * 32 + koff);
#pragma unroll
    for (int nt = 0; nt < 4; ++nt) {
      bf8v bw = *(const bf8v*)(wb + OFF_O + (size_t)(nt * 16 + c16) * 64 +
                               ks * 32 + koff);
      o[nt] = MFMA16(pa, bw, o[nt]);
    }
  }

  float* obase = out + (size_t)b * T * 1024 + h * 64;
#pragma unroll
  for (int nt = 0; nt < 4; ++nt) {
#pragma unroll
    for (int r = 0; r < 4; ++r)
      obase[(size_t)(t0 + lrow + r) * 1024 + nt * 16 + c16] = o[nt][r];
  }
}

} // namespace

extern "C" void kernel_launch(void* const* d_in, const int* in_sizes, int n_in,
                              void* d_out, int out_size, void* d_ws, size_t ws_size,
                              hipStream_t stream) {
  (void)in_sizes; (void)n_in; (void)out_size; (void)ws_size;
  const float* x     = (const float*)d_in[0];
  const float* W_DQ  = (const float*)d_in[1];
  const float* W_UQ  = (const float*)d_in[2];
  const float* W_DKV = (const float*)d_in[3];
  const float* W_UKV = (const float*)d_in[4];
  const float* W_QR  = (const float*)d_in[5];
  const float* W_KR  = (const float*)d_in[6];
  const float* W_O   = (const float*)d_in[7];
  const float* qnw   = (const float*)d_in[8];
  const float* knw   = (const float*)d_in[9];
  float* out = (float*)d_out;

  short* ws = (short*)d_ws;
  short* xb  = ws;                          // 4,194,304
  short* qb  = ws + (size_t)4194304;        // 8,388,608
  short* kb  = ws + (size_t)12582912;       // 8,388,608
  short* vtg = ws + (size_t)20971520;       // 4,194,304
  short* wb  = ws + (size_t)25165824;       // 274,432

  cvt_x_kernel<<<4096, 256, 0, stream>>>(x, xb);
  cvt_w_kernel<<<W_TOTAL / 256, 256, 0, stream>>>(W_DQ, W_UQ, W_DKV, W_UKV,
                                                  W_QR, W_KR, W_O, wb);
  dim3 pgrid(T / 128, 32); // 128-row tiles
  proj_q_mfma<<<pgrid, 256, 0, stream>>>(xb, wb, qnw, qb);
  proj_kv_mfma<<<pgrid, 256, 0, stream>>>(xb, wb, knw, kb, vtg);
  attn_mfma<<<1024, 256, 0, stream>>>(qb, kb, vtg, wb, out);
}

// Round 13
// 144.562 us; speedup vs baseline: 1.2480x; 1.0870x over previous
//
#include <hip/hip_runtime.h>
#include <hip/hip_bf16.h>
#include <math.h>

namespace {

constexpr int T  = 2048;
constexpr int HD = 64;
constexpr float EPS = 1.1920929e-07f;
// SCALE * log2(e), folded into q at proj_q write time -> attn softmax runs in exp2 domain
constexpr float PS = 0.125f * 1.44269504f;

// bf16 weight pool offsets (in elements)
constexpr int OFF_DQ  = 0;       // 512*64
constexpr int OFF_UQ  = 32768;   // 64*512
constexpr int OFF_DKV = 65536;   // 1024*64
constexpr int OFF_UKV = 131072;  // 128*1024
constexpr int OFF_QR  = 262144;  // 64*64
constexpr int OFF_KR  = 266240;  // 64*64
constexpr int OFF_O   = 270336;  // 64*64
constexpr int W_TOTAL = 274432;

typedef __attribute__((ext_vector_type(8))) short bf8v;  // 8 bf16 (4 VGPR)
typedef __attribute__((ext_vector_type(4))) float f4v;   // MFMA C/D

#define MFMA16(a, b, c) __builtin_amdgcn_mfma_f32_16x16x32_bf16((a), (b), (c), 0, 0, 0)

// full-strength barrier for raw s_barrier use (rule #18 class): compiler
// memory fences both sides so gload_lds issues can't be hoisted across.
#define HARD_BARRIER()                                   \
  do {                                                   \
    asm volatile("" ::: "memory");                       \
    __builtin_amdgcn_s_barrier();                        \
    asm volatile("" ::: "memory");                       \
    __builtin_amdgcn_sched_barrier(0);                   \
  } while (0)

__device__ __forceinline__ short f2bf(float f) {
  union { float f; unsigned u; } v; v.f = f;
  unsigned r = v.u + 0x7FFFu + ((v.u >> 16) & 1u); // RNE
  return (short)(r >> 16);
}

__device__ __forceinline__ f4v z4() { f4v z = {0.f, 0.f, 0.f, 0.f}; return z; }

// XOR swizzles: spread row-strided b128 accesses across banks (m214 pattern)
__device__ __forceinline__ int swz128(int b) { return b ^ (((b >> 7) & 7) << 4); }
__device__ __forceinline__ int swz256(int b) { return b ^ (((b >> 8) & 7) << 4); }

__device__ __forceinline__ bf8v ldA128(const short* lds, int row, int k) {
  return *(const bf8v*)((const char*)lds + swz128(row * 128 + k * 2));
}
__device__ __forceinline__ bf8v ldA256(const short* lds, int row, int k) {
  return *(const bf8v*)((const char*)lds + swz256(row * 256 + k * 2));
}

// scatter a 16x16 D-fragment (col=lane&15, row=(lane>>4)*4+r) as bf16 into LDS
__device__ __forceinline__ void scat128(short* lds, int row0, int lane, int nt, f4v v) {
  int col = nt * 16 + (lane & 15);
  int r0 = row0 + ((lane >> 4) << 2);
#pragma unroll
  for (int r = 0; r < 4; ++r)
    *(short*)((char*)lds + swz128((r0 + r) * 128 + col * 2)) = f2bf(v[r]);
}
__device__ __forceinline__ void scat256(short* lds, int row0, int lane, int col, f4v v) {
  int r0 = row0 + ((lane >> 4) << 2);
#pragma unroll
  for (int r = 0; r < 4; ++r)
    *(short*)((char*)lds + swz256((r0 + r) * 256 + col * 2)) = f2bf(v[r]);
}

// async global->LDS, 16B per lane; LDS dest wave-uniform base + lane*16
__device__ __forceinline__ void gload_lds16(const void* g, void* l) {
  __builtin_amdgcn_global_load_lds(
      (const __attribute__((address_space(1))) void*)g,
      (__attribute__((address_space(3))) void*)l, 16, 0, 0);
}

// ---------------------------------------------------------------------------
// conversions
// ---------------------------------------------------------------------------
__global__ __launch_bounds__(256) void cvt_x_kernel(const float* __restrict__ x,
                                                    short* __restrict__ xb) {
  int i = (blockIdx.x * 256 + threadIdx.x) * 4; // over x linear (B,T,D)
  float4 v = *(const float4*)(x + i);
  int d = i & 1023, t = (i >> 10) & 2047, b = i >> 21;
  int h = d >> 6, dd = d & 63;
  short4 o;
  o.x = f2bf(v.x); o.y = f2bf(v.y); o.z = f2bf(v.z); o.w = f2bf(v.w);
  *(short4*)(xb + ((((size_t)b * 16 + h) * T + t) * 64 + dd)) = o;
}

__global__ __launch_bounds__(256) void cvt_w_kernel(
    const float* __restrict__ W_DQ, const float* __restrict__ W_UQ,
    const float* __restrict__ W_DKV, const float* __restrict__ W_UKV,
    const float* __restrict__ W_QR, const float* __restrict__ W_KR,
    const float* __restrict__ W_O, short* __restrict__ wb) {
  int i = blockIdx.x * 256 + threadIdx.x;
  const float* src; int off;
  if      (i < 32768)  { src = W_DQ;  off = 0; }
  else if (i < 65536)  { src = W_UQ;  off = 32768; }
  else if (i < 131072) { src = W_DKV; off = 65536; }
  else if (i < 262144) { src = W_UKV; off = 131072; }
  else if (i < 266240) { src = W_QR;  off = 262144; }
  else if (i < 270336) { src = W_KR;  off = 266240; }
  else                 { src = W_O;   off = 270336; }
  wb[i] = f2bf(src[i - off]);
}

// ---------------------------------------------------------------------------
// proj_q v2 (unchanged; __syncthreads-based, airtight)
// ---------------------------------------------------------------------------
__global__ __launch_bounds__(256) void proj_q_mfma(
    const short* __restrict__ xb, const short* __restrict__ wb,
    const float* __restrict__ qnw, short* __restrict__ qb) {
  __shared__ __attribute__((aligned(16))) short Xs[128 * 64];   // 16KB
  __shared__ __attribute__((aligned(16))) short Wd[2][64 * 64]; // 2x8KB
  __shared__ __attribute__((aligned(16))) short Wu[2][64 * 64]; // 2x8KB
  __shared__ __attribute__((aligned(16))) short Cs[128 * 64];   // 16KB

  const int tid = threadIdx.x, lane = tid & 63, w = tid >> 6;
  const int bh = blockIdx.y, t0 = blockIdx.x * 128;
  const int c16 = lane & 15;
  const int koff = (lane >> 4) << 3;

  auto stageWd = [&](int lc) {
    const char* src = (const char*)(wb + OFF_DQ + lc * 64 * 64);
    char* dst = (char*)&Wd[lc & 1][0];
#pragma unroll
    for (int p = 0; p < 2; ++p) {
      const int base = p * 256 + w * 64;
      gload_lds16(src + swz128((base + lane) * 16), dst + base * 16);
    }
  };
  auto stageWu = [&](int lc) {
    const char* src = (const char*)(wb + OFF_UQ + lc * 64);
    char* dst = (char*)&Wu[lc & 1][0];
#pragma unroll
    for (int p = 0; p < 2; ++p) {
      const int base = p * 256 + w * 64;
      const int lb = swz128((base + lane) * 16);
      gload_lds16(src + (size_t)(lb >> 7) * 1024 + (lb & 127), dst + base * 16);
    }
  };

  {
    const char* src = (const char*)(xb + ((size_t)bh * T + t0) * 64);
#pragma unroll
    for (int p = 0; p < 4; ++p) {
      const int base = p * 256 + w * 64;
      gload_lds16(src + swz128((base + lane) * 16), (char*)Xs + base * 16);
    }
  }
  stageWd(0);
  stageWu(0);
  __syncthreads();

  f4v acc[2][4];
#pragma unroll
  for (int rg = 0; rg < 2; ++rg)
#pragma unroll
    for (int nt = 0; nt < 4; ++nt) acc[rg][nt] = z4();

  for (int lc = 0; lc < 8; ++lc) {
    if (lc < 7) { stageWd(lc + 1); stageWu(lc + 1); }
    else {
      const char* src = (const char*)(wb + OFF_QR);
      char* dst = (char*)&Wd[0][0];
#pragma unroll
      for (int p = 0; p < 2; ++p) {
        const int base = p * 256 + w * 64;
        gload_lds16(src + swz128((base + lane) * 16), dst + base * 16);
      }
    }
    const short* Wdc = &Wd[lc & 1][0];
    const short* Wuc = &Wu[lc & 1][0];

    f4v cc[2][4];
#pragma unroll
    for (int rg = 0; rg < 2; ++rg)
#pragma unroll
      for (int nt = 0; nt < 4; ++nt) cc[rg][nt] = z4();
#pragma unroll
    for (int rg = 0; rg < 2; ++rg)
#pragma unroll
      for (int ks = 0; ks < 2; ++ks) {
        bf8v a = ldA128(Xs, w * 32 + rg * 16 + c16, ks * 32 + koff);
#pragma unroll
        for (int nt = 0; nt < 4; ++nt) {
          bf8v b = ldA128(Wdc, nt * 16 + c16, ks * 32 + koff);
          cc[rg][nt] = MFMA16(a, b, cc[rg][nt]);
        }
      }
#pragma unroll
    for (int rg = 0; rg < 2; ++rg)
#pragma unroll
      for (int nt = 0; nt < 4; ++nt) scat128(Cs, w * 32 + rg * 16, lane, nt, cc[rg][nt]);
#pragma unroll
    for (int rg = 0; rg < 2; ++rg)
#pragma unroll
      for (int ks = 0; ks < 2; ++ks) {
        bf8v a = ldA128(Cs, w * 32 + rg * 16 + c16, ks * 32 + koff);
#pragma unroll
        for (int nt = 0; nt < 4; ++nt) {
          bf8v b = ldA128(Wuc, nt * 16 + c16, ks * 32 + koff);
          acc[rg][nt] = MFMA16(a, b, acc[rg][nt]);
        }
      }
    __syncthreads();
  }

  float w4[4];
#pragma unroll
  for (int nt = 0; nt < 4; ++nt) w4[nt] = qnw[nt * 16 + c16] * PS;
#pragma unroll
  for (int rg = 0; rg < 2; ++rg)
#pragma unroll
    for (int r = 0; r < 4; ++r) {
      float ss = 0.f;
#pragma unroll
      for (int nt = 0; nt < 4; ++nt) ss += acc[rg][nt][r] * acc[rg][nt][r];
      ss += __shfl_xor(ss, 1, 16); ss += __shfl_xor(ss, 2, 16);
      ss += __shfl_xor(ss, 4, 16); ss += __shfl_xor(ss, 8, 16);
      float inv = rsqrtf(ss * (1.f / 64.f) + EPS);
#pragma unroll
      for (int nt = 0; nt < 4; ++nt) acc[rg][nt][r] *= inv * w4[nt];
    }

#pragma unroll
  for (int rg = 0; rg < 2; ++rg)
#pragma unroll
    for (int nt = 0; nt < 4; ++nt) scat128(Cs, w * 32 + rg * 16, lane, nt, acc[rg][nt]);

  f4v qr[2][4];
#pragma unroll
  for (int rg = 0; rg < 2; ++rg)
#pragma unroll
    for (int nt = 0; nt < 4; ++nt) qr[rg][nt] = z4();
#pragma unroll
  for (int rg = 0; rg < 2; ++rg)
#pragma unroll
    for (int ks = 0; ks < 2; ++ks) {
      bf8v a = ldA128(Cs, w * 32 + rg * 16 + c16, ks * 32 + koff);
#pragma unroll
      for (int nt = 0; nt < 4; ++nt) {
        bf8v b = ldA128(&Wd[0][0], nt * 16 + c16, ks * 32 + koff);
        qr[rg][nt] = MFMA16(a, b, qr[rg][nt]);
      }
    }
#pragma unroll
  for (int rg = 0; rg < 2; ++rg)
#pragma unroll
    for (int nt = 0; nt < 4; ++nt) scat128(Xs, w * 32 + rg * 16, lane, nt, qr[rg][nt]);
  __syncthreads();

  short* qdst = qb + ((size_t)bh * T + t0) * 128;
#pragma unroll
  for (int p = 0; p < 4; ++p) {
    int ci = tid + p * 256;
    int r = ci >> 3, c = (ci & 7) << 3;
    *(bf8v*)(qdst + (size_t)r * 128 + c) =
        *(const bf8v*)((const char*)Cs + swz128(ci * 16));
    *(bf8v*)(qdst + (size_t)r * 128 + 64 + c) =
        *(const bf8v*)((const char*)Xs + swz128(ci * 16));
  }
}

// ---------------------------------------------------------------------------
// proj_kv v2 (unchanged)
// ---------------------------------------------------------------------------
__global__ __launch_bounds__(256) void proj_kv_mfma(
    const short* __restrict__ xb, const short* __restrict__ wb,
    const float* __restrict__ knw, short* __restrict__ kb, short* __restrict__ vtg) {
  __shared__ __attribute__((aligned(16))) short Xs[128 * 64];    // 16KB
  __shared__ __attribute__((aligned(16))) short Wd[2][64 * 64];  // 2x8KB
  __shared__ __attribute__((aligned(16))) short Wu[2][128 * 64]; // 2x16KB (-> Ko 32KB)
  __shared__ __attribute__((aligned(16))) short Cs[128 * 64];    // 16KB (-> Vt)

  const int tid = threadIdx.x, lane = tid & 63, w = tid >> 6;
  const int bh = blockIdx.y, t0 = blockIdx.x * 128;
  const int c16 = lane & 15;
  const int g4 = lane >> 4;
  const int koff = g4 << 3;
  const int rg4 = g4 << 2;

  auto stageWd = [&](int lc) {
    const char* src = (const char*)(wb + OFF_DKV + lc * 64 * 64);
    char* dst = (char*)&Wd[lc & 1][0];
#pragma unroll
    for (int p = 0; p < 2; ++p) {
      const int base = p * 256 + w * 64;
      gload_lds16(src + swz128((base + lane) * 16), dst + base * 16);
    }
  };
  auto stageWu = [&](int lc) {
    const char* src = (const char*)(wb + OFF_UKV + lc * 64);
    char* dst = (char*)&Wu[lc & 1][0];
#pragma unroll
    for (int p = 0; p < 4; ++p) {
      const int base = p * 256 + w * 64;
      const int lb = swz128((base + lane) * 16);
      gload_lds16(src + (size_t)(lb >> 7) * 2048 + (lb & 127), dst + base * 16);
    }
  };

  {
    const char* src = (const char*)(xb + ((size_t)bh * T + t0) * 64);
#pragma unroll
    for (int p = 0; p < 4; ++p) {
      const int base = p * 256 + w * 64;
      gload_lds16(src + swz128((base + lane) * 16), (char*)Xs + base * 16);
    }
  }
  stageWd(0);
  stageWu(0);
  __syncthreads();

  f4v acc[2][8];
#pragma unroll
  for (int rg = 0; rg < 2; ++rg)
#pragma unroll
    for (int nt = 0; nt < 8; ++nt) acc[rg][nt] = z4();

  for (int lc = 0; lc < 16; ++lc) {
    if (lc < 15) { stageWd(lc + 1); stageWu(lc + 1); }
    else {
      const char* src = (const char*)(wb + OFF_KR);
      char* dst = (char*)&Wd[0][0];
#pragma unroll
      for (int p = 0; p < 2; ++p) {
        const int base = p * 256 + w * 64;
        gload_lds16(src + swz128((base + lane) * 16), dst + base * 16);
      }
    }
    const short* Wdc = &Wd[lc & 1][0];
    const short* Wuc = &Wu[lc & 1][0];

    f4v cc[2][4];
#pragma unroll
    for (int rg = 0; rg < 2; ++rg)
#pragma unroll
      for (int nt = 0; nt < 4; ++nt) cc[rg][nt] = z4();
#pragma unroll
    for (int rg = 0; rg < 2; ++rg)
#pragma unroll
      for (int ks = 0; ks < 2; ++ks) {
        bf8v a = ldA128(Xs, w * 32 + rg * 16 + c16, ks * 32 + koff);
#pragma unroll
        for (int nt = 0; nt < 4; ++nt) {
          bf8v b = ldA128(Wdc, nt * 16 + c16, ks * 32 + koff);
          cc[rg][nt] = MFMA16(a, b, cc[rg][nt]);
        }
      }
#pragma unroll
    for (int rg = 0; rg < 2; ++rg)
#pragma unroll
      for (int nt = 0; nt < 4; ++nt) scat128(Cs, w * 32 + rg * 16, lane, nt, cc[rg][nt]);
#pragma unroll
    for (int rg = 0; rg < 2; ++rg)
#pragma unroll
      for (int ks = 0; ks < 2; ++ks) {
        bf8v a = ldA128(Cs, w * 32 + rg * 16 + c16, ks * 32 + koff);
#pragma unroll
        for (int nt = 0; nt < 8; ++nt) {
          bf8v b = ldA128(Wuc, nt * 16 + c16, ks * 32 + koff);
          acc[rg][nt] = MFMA16(a, b, acc[rg][nt]);
        }
      }
    __syncthreads();
  }

  float w4[4];
#pragma unroll
  for (int nt = 0; nt < 4; ++nt) w4[nt] = knw[nt * 16 + c16];
#pragma unroll
  for (int rg = 0; rg < 2; ++rg)
#pragma unroll
    for (int r = 0; r < 4; ++r) {
      float ss = 0.f;
#pragma unroll
      for (int nt = 0; nt < 4; ++nt) ss += acc[rg][nt][r] * acc[rg][nt][r];
      ss += __shfl_xor(ss, 1, 16); ss += __shfl_xor(ss, 2, 16);
      ss += __shfl_xor(ss, 4, 16); ss += __shfl_xor(ss, 8, 16);
      float inv = rsqrtf(ss * (1.f / 64.f) + EPS);
#pragma unroll
      for (int nt = 0; nt < 4; ++nt) acc[rg][nt][r] *= inv * w4[nt];
    }

  short* Ko = &Wu[0][0];
#pragma unroll
  for (int rg = 0; rg < 2; ++rg)
#pragma unroll
    for (int nt = 0; nt < 4; ++nt)
      scat256(Ko, w * 32 + rg * 16, lane, nt * 16 + c16, acc[rg][nt]);

#pragma unroll
  for (int rg = 0; rg < 2; ++rg)
#pragma unroll
    for (int nt = 0; nt < 4; ++nt) {
      const int d = nt * 16 + c16;
      const int tc0 = w * 32 + rg * 16 + rg4;
#pragma unroll
      for (int r = 0; r < 4; ++r)
        *(short*)((char*)Cs + swz256(d * 256 + (tc0 + r) * 2)) =
            f2bf(acc[rg][4 + nt][r]);
    }

  f4v kr[2][4];
#pragma unroll
  for (int rg = 0; rg < 2; ++rg)
#pragma unroll
    for (int nt = 0; nt < 4; ++nt) kr[rg][nt] = z4();
#pragma unroll
  for (int rg = 0; rg < 2; ++rg)
#pragma unroll
    for (int ks = 0; ks < 2; ++ks) {
      bf8v a = ldA128(Xs, w * 32 + rg * 16 + c16, ks * 32 + koff);
#pragma unroll
      for (int nt = 0; nt < 4; ++nt) {
        bf8v b = ldA128(&Wd[0][0], nt * 16 + c16, ks * 32 + koff);
        kr[rg][nt] = MFMA16(a, b, kr[rg][nt]);
      }
    }
#pragma unroll
  for (int rg = 0; rg < 2; ++rg)
#pragma unroll
    for (int nt = 0; nt < 4; ++nt)
      scat256(Ko, w * 32 + rg * 16, lane, 64 + nt * 16 + c16, kr[rg][nt]);
  __syncthreads();

  short* kdst = kb + ((size_t)bh * T + t0) * 128;
#pragma unroll
  for (int p = 0; p < 8; ++p) {
    int ci = tid + p * 256;
    int r = ci >> 4, c = (ci & 15) << 3;
    *(bf8v*)(kdst + (size_t)r * 128 + c) =
        *(const bf8v*)((const char*)Ko + swz256(ci * 16));
  }
#pragma unroll
  for (int p = 0; p < 4; ++p) {
    int ci = tid + p * 256;
    int d = ci >> 4, c = (ci & 15) << 3;
    *(bf8v*)(vtg + ((size_t)bh * 64 + d) * T + t0 + c) =
        *(const bf8v*)((const char*)Cs + swz256(ci * 16));
  }
}

// ---------------------------------------------------------------------------
// attn v9: v7c pipeline (3 K bufs staged 2 ahead, coop V 1 ahead, counted
// vmcnt(6), HARD_BARRIERs) + QBLK=128: each block handles 128 q-rows (two
// 64-row chunks rg=0,1 per wave) -> 2x MFMA per staged tile & barrier pair,
// ~2x less K/V staging traffic. 512 blocks (16 qblocks x 32 bh), CU-balanced
// qb permutation (co-residents sum to 34 tiles), XCD-clustered bh.
// LDS 80KB (Ks[3]48 + Vs[2]16 + Ps16) -> 2 blocks/CU.
// ---------------------------------------------------------------------------
__global__ __launch_bounds__(256) void attn_mfma(
    const short* __restrict__ qbuf, const short* __restrict__ kb,
    const short* __restrict__ vtg, const short* __restrict__ wb,
    float* __restrict__ out) {
  __shared__ __attribute__((aligned(16))) short Ks[3][64 * 128]; // swz256, 16KB ea
  __shared__ __attribute__((aligned(16))) short Vs[2][64 * 64];  // swz128, 8KB ea
  __shared__ __attribute__((aligned(16))) short Ps[128 * 64];    // swz128, 16KB

  const int tid = threadIdx.x, lane = tid & 63, w = tid >> 6;
  const int lin = blockIdx.x;           // [0,512)
  const int g = lin >> 5;               // qblock group 0..15
  const int qblk = (g < 8) ? g : 23 - g; // CU-balanced: qb(g)+qb(g+8)=15
  const int inner = lin & 31;
  const int bh = (inner & 7) + 8 * (inner >> 3); // XCD-clustered (4 bh/XCD)

  const int b = bh >> 4, h = bh & 15;
  const int c16 = lane & 15;
  const int g4 = lane >> 4;
  const int koff = g4 << 3;
  const int rg4 = g4 << 2;
  const int lbase = lane & 48;

  const short* kbh = kb + (size_t)bh * T * 128;
  const short* vbh = vtg + (size_t)bh * 64 * T;
  const int t0 = qblk * 128;
  const int qt0 = 2 * qblk;     // chunk 0's last tile
  const int NT = 2 * qblk + 2;  // tiles needed (chunk 1's last is NT-1)

  // Q fragments for both 64-row chunks
  bf8v aq[2][4];
#pragma unroll
  for (int rg = 0; rg < 2; ++rg) {
    const short* qsrc = qbuf + ((size_t)bh * T + t0 + rg * 64 + w * 16 + c16) * 128;
#pragma unroll
    for (int ks = 0; ks < 4; ++ks) aq[rg][ks] = *(const bf8v*)(qsrc + ks * 32 + koff);
  }

  auto ktile = [&](int gg) { return (gg < NT) ? gg : 0; };

  auto stageK = [&](int gg) { // 4 gload_lds per wave
    const int jt = ktile(gg);
    const char* src = (const char*)(kbh + jt * 64 * 128);
    char* dst = (char*)&Ks[gg % 3][0];
#pragma unroll
    for (int p = 0; p < 4; ++p) {
      const int base = p * 256 + w * 64;
      gload_lds16(src + swz256((base + lane) * 16), dst + base * 16);
    }
  };
  auto stageV = [&](int gg) { // 2 gload_lds per wave
    const int jt = ktile(gg);
    char* dst = (char*)&Vs[gg & 1][0];
#pragma unroll
    for (int p = 0; p < 2; ++p) {
      const int base = p * 256 + w * 64;
      const int tb = swz128((base + lane) * 16);
      const int r = tb >> 7, cb = tb & 127;
      gload_lds16((const char*)vbh + ((size_t)r * T + jt * 64) * 2 + cb,
                  dst + base * 16);
    }
  };

  stageK(0);
  stageK(1);
  stageV(0);
  asm volatile("s_waitcnt vmcnt(6)" ::: "memory");
  HARD_BARRIER();

  f4v ctx[2][4];
  float m[2] = {-INFINITY, -INFINITY}, l[2] = {0.f, 0.f};
#pragma unroll
  for (int rg = 0; rg < 2; ++rg)
#pragma unroll
    for (int nt = 0; nt < 4; ++nt) ctx[rg][nt] = z4();

  for (int gg = 0; gg < NT; ++gg) {
    const short* Kb = &Ks[gg % 3][0];
    const short* Vb = &Vs[gg & 1][0];
    stageK(gg + 2);
    stageV(gg + 1);

    const int j0 = gg * 64;

#pragma unroll
    for (int rg = 0; rg < 2; ++rg) {
      if (rg == 0 && gg > qt0) continue; // chunk 0 done (only on final tile)
      const int qglob = t0 + rg * 64 + w * 16 + c16;
      const bool diag = (gg == qt0 + rg);

      // Swapped QK^T: s[nt][r] = S[kpos=j0+nt*16+rg4+r][qglob]
      f4v s[4];
#pragma unroll
      for (int nt = 0; nt < 4; ++nt) s[nt] = z4();
#pragma unroll
      for (int ks = 0; ks < 4; ++ks) {
#pragma unroll
        for (int nt = 0; nt < 4; ++nt) {
          bf8v bk = ldA256(Kb, nt * 16 + c16, ks * 32 + koff);
          s[nt] = MFMA16(bk, aq[rg][ks], s[nt]); // A=K, B=Q
        }
      }

      if (diag) {
#pragma unroll
        for (int nt = 0; nt < 4; ++nt)
#pragma unroll
          for (int r = 0; r < 4; ++r)
            if (j0 + nt * 16 + rg4 + r > qglob) s[nt][r] = -INFINITY;
      }

      // row max: in-lane tree + 2 cross-group shfl
      f4v mnt;
#pragma unroll
      for (int r = 0; r < 4; ++r)
        mnt[r] = fmaxf(fmaxf(s[0][r], s[1][r]), fmaxf(s[2][r], s[3][r]));
      float mx = fmaxf(fmaxf(mnt[0], mnt[1]), fmaxf(mnt[2], mnt[3]));
      mx = fmaxf(mx, __shfl_xor(mx, 16));
      mx = fmaxf(mx, __shfl_xor(mx, 32));

      // defer-max rescale (THR=8, exp2 domain)
      if (__any(mx - m[rg] > 8.f)) {
        const float mn  = fmaxf(m[rg], mx);
        const float scl = __builtin_amdgcn_exp2f(m[rg] - mn);
        l[rg] *= scl; m[rg] = mn;
        float sr[4];
#pragma unroll
        for (int r = 0; r < 4; ++r) sr[r] = __shfl(scl, lbase + rg4 + r);
#pragma unroll
        for (int nt = 0; nt < 4; ++nt)
#pragma unroll
          for (int r = 0; r < 4; ++r) ctx[rg][nt][r] *= sr[r];
      }

      // p = exp2(s - m); in-lane sum + 2 shfl
#pragma unroll
      for (int nt = 0; nt < 4; ++nt)
#pragma unroll
        for (int r = 0; r < 4; ++r)
          s[nt][r] = __builtin_amdgcn_exp2f(s[nt][r] - m[rg]);
      f4v sv = s[0] + s[1] + s[2] + s[3];
      float rs = (sv[0] + sv[1]) + (sv[2] + sv[3]);
      rs += __shfl_xor(rs, 16);
      rs += __shfl_xor(rs, 32);
      l[rg] += rs;

      // P -> LDS rows rg*64 + w*16 + c16 (wave-private): 4x ds_write_b64
      {
        char* prow = (char*)Ps;
        const int rbase = (rg * 64 + w * 16 + c16) * 128 + koff;
#pragma unroll
        for (int nt = 0; nt < 4; ++nt) {
          __hip_bfloat162 h0 = __float22bfloat162_rn(make_float2(s[nt][0], s[nt][1]));
          __hip_bfloat162 h1 = __float22bfloat162_rn(make_float2(s[nt][2], s[nt][3]));
          uint2 d;
          d.x = *(unsigned int*)&h0;
          d.y = *(unsigned int*)&h1;
          *(uint2*)(prow + swz128(rbase + nt * 32)) = d;
        }
      }
    }

    // drain prev tile's 6 loads (leaves this tile's 6 in flight), then barrier
    // so ALL waves' V(gg) chunks are landed before any PV read
    asm volatile("s_waitcnt vmcnt(6)" ::: "memory");
    HARD_BARRIER();

#pragma unroll
    for (int rg = 0; rg < 2; ++rg) {
      if (rg == 0 && gg > qt0) continue;
#pragma unroll
      for (int ks = 0; ks < 2; ++ks) {
        bf8v pa = ldA128(Ps, rg * 64 + w * 16 + c16, ks * 32 + koff);
#pragma unroll
        for (int nt = 0; nt < 4; ++nt) {
          bf8v vf = ldA128(Vb, nt * 16 + c16, ks * 32 + koff);
          ctx[rg][nt] = MFMA16(pa, vf, ctx[rg][nt]);
        }
      }
    }

    HARD_BARRIER(); // buffer-reuse WAR fence
  }

  // epilogue: per chunk, ctx/l -> Ps rows, out = ctx @ W_O^T
  float* obase = out + (size_t)b * T * 1024 + h * 64;
#pragma unroll
  for (int rg = 0; rg < 2; ++rg) {
    float linv[4];
#pragma unroll
    for (int r = 0; r < 4; ++r) linv[r] = 1.0f / __shfl(l[rg], lbase + rg4 + r);
    f4v cn[4];
#pragma unroll
    for (int nt = 0; nt < 4; ++nt)
#pragma unroll
      for (int r = 0; r < 4; ++r) cn[nt][r] = ctx[rg][nt][r] * linv[r];
#pragma unroll
    for (int nt = 0; nt < 4; ++nt) scat128(Ps, rg * 64 + w * 16, lane, nt, cn[nt]);

    f4v o[4];
#pragma unroll
    for (int nt = 0; nt < 4; ++nt) o[nt] = z4();
#pragma unroll
    for (int ks = 0; ks < 2; ++ks) {
      bf8v pa = ldA128(Ps, rg * 64 + w * 16 + c16, ks * 32 + koff);
#pragma unroll
      for (int nt = 0; nt < 4; ++nt) {
        bf8v bw = *(const bf8v*)(wb + OFF_O + (size_t)(nt * 16 + c16) * 64 +
                                 ks * 32 + koff);
        o[nt] = MFMA16(pa, bw, o[nt]);
      }
    }

#pragma unroll
    for (int nt = 0; nt < 4; ++nt) {
#pragma unroll
      for (int r = 0; r < 4; ++r)
        obase[(size_t)(t0 + rg * 64 + w * 16 + rg4 + r) * 1024 + nt * 16 + c16] =
            o[nt][r];
    }
  }
}

} // namespace

extern "C" void kernel_launch(void* const* d_in, const int* in_sizes, int n_in,
                              void* d_out, int out_size, void* d_ws, size_t ws_size,
                              hipStream_t stream) {
  (void)in_sizes; (void)n_in; (void)out_size; (void)ws_size;
  const float* x     = (const float*)d_in[0];
  const float* W_DQ  = (const float*)d_in[1];
  const float* W_UQ  = (const float*)d_in[2];
  const float* W_DKV = (const float*)d_in[3];
  const float* W_UKV = (const float*)d_in[4];
  const float* W_QR  = (const float*)d_in[5];
  const float* W_KR  = (const float*)d_in[6];
  const float* W_O   = (const float*)d_in[7];
  const float* qnw   = (const float*)d_in[8];
  const float* knw   = (const float*)d_in[9];
  float* out = (float*)d_out;

  short* ws = (short*)d_ws;
  short* xb  = ws;                          // 4,194,304
  short* qb  = ws + (size_t)4194304;        // 8,388,608
  short* kb  = ws + (size_t)12582912;       // 8,388,608
  short* vtg = ws + (size_t)20971520;       // 4,194,304
  short* wb  = ws + (size_t)25165824;       // 274,432

  cvt_x_kernel<<<4096, 256, 0, stream>>>(x, xb);
  cvt_w_kernel<<<W_TOTAL / 256, 256, 0, stream>>>(W_DQ, W_UQ, W_DKV, W_UKV,
                                                  W_QR, W_KR, W_O, wb);
  dim3 pgrid(T / 128, 32); // 128-row tiles
  proj_q_mfma<<<pgrid, 256, 0, stream>>>(xb, wb, qnw, qb);
  proj_kv_mfma<<<pgrid, 256, 0, stream>>>(xb, wb, knw, kb, vtg);
  attn_mfma<<<512, 256, 0, stream>>>(qb, kb, vtg, wb, out);
}